// Round 5
// baseline (692.307 us; speedup 1.0000x reference)
//
#include <hip/hip_runtime.h>
#include <hip/hip_bf16.h>

// Sizes (fixed by the reference)
#define BATCH 8192
#define DIM   128
#define NPAT  64
#define VOCAB 32000
#define NTILES (VOCAB / 16)   // 2000 n-tiles of 16 cols

typedef __attribute__((ext_vector_type(8))) short short8;   // 8 bf16 = 4 VGPRs
typedef __attribute__((ext_vector_type(4))) float f32x4;    // MFMA accum

// ---------------------------------------------------------------------------
// Phase A: per-row attention/softmax/rec/self-gate, all f32, output gated bf16.
// One wave per batch row, 4 rows (4 waves) per block.  (unchanged, ~15 us)
// ---------------------------------------------------------------------------
__global__ __launch_bounds__(256) void phaseA_kernel(
    const float* __restrict__ x,            // [B, D]
    const float* __restrict__ attn_w,       // [D, P]
    const float* __restrict__ attn_b,       // [P]
    const float* __restrict__ pattern_dict, // [P, D]
    const float* __restrict__ self_w,       // [D, D]
    const float* __restrict__ self_b,       // [D]
    __hip_bfloat16* __restrict__ gated)     // [B, D] bf16 out
{
    __shared__ float xs[4][DIM];
    __shared__ float wls[4][NPAT];
    __shared__ float recs[4][DIM];

    const int lane = threadIdx.x & 63;
    const int wid  = threadIdx.x >> 6;
    const int row  = blockIdx.x * 4 + wid;

    xs[wid][lane]      = x[row * DIM + lane];
    xs[wid][lane + 64] = x[row * DIM + 64 + lane];
    __syncthreads();

    float acc = attn_b[lane];
#pragma unroll 8
    for (int d = 0; d < DIM; ++d)
        acc += xs[wid][d] * attn_w[d * NPAT + lane];

    float m = acc;
#pragma unroll
    for (int o = 32; o; o >>= 1) m = fmaxf(m, __shfl_xor(m, o));
    float e = expf(acc - m);
    float s = e;
#pragma unroll
    for (int o = 32; o; o >>= 1) s += __shfl_xor(s, o);
    float w = e / s;
    wls[wid][lane] = w;
    __syncthreads();

    float r0 = 0.f, r1 = 0.f;
#pragma unroll 8
    for (int p = 0; p < NPAT; ++p) {
        float wp = wls[wid][p];
        r0 += wp * pattern_dict[p * DIM + lane];
        r1 += wp * pattern_dict[p * DIM + 64 + lane];
    }
    recs[wid][lane]      = r0;
    recs[wid][lane + 64] = r1;
    __syncthreads();

    float s0 = self_b[lane], s1 = self_b[lane + 64];
#pragma unroll 8
    for (int k = 0; k < DIM; ++k) {
        float rk = recs[wid][k];
        s0 += rk * self_w[k * DIM + lane];
        s1 += rk * self_w[k * DIM + 64 + lane];
    }

    float p0 = s0 - r0, p1 = s1 - r1;
    float ss = p0 * p0 + p1 * p1;
#pragma unroll
    for (int o = 32; o; o >>= 1) ss += __shfl_xor(ss, o);
    float mag = sqrtf(ss);
    float g = 1.f / (1.f + expf(-mag));

    gated[row * DIM + lane]      = __float2bfloat16(r0 * g);
    gated[row * DIM + 64 + lane] = __float2bfloat16(r1 * g);
}

// ---------------------------------------------------------------------------
// Repack: out_w [D=128, V] f32 -> Bf fragment-major bf16.
// Bf element index = ((tile*4 + ks)*64 + lane)*8 + j  (16 B per lane), where
//   tile = n>>4, lane = kq*16 + r16, and the 8 bf16 are
//   Bt[n = tile*16 + r16][k = ks*32 + kq*8 + j]  (= out_w[k][n]).
// So each GEMM B-load is ONE contiguous 1-KB wave load. LDS tile transpose.
// ---------------------------------------------------------------------------
__global__ __launch_bounds__(256) void repack_w_kernel(
    const float* __restrict__ out_w,        // [D, V]
    __hip_bfloat16* __restrict__ Bf)        // fragment-major [NTILES*4*64*8]
{
    __shared__ __hip_bfloat16 tile[64][136]; // [n-local][k], padded row

    const int t  = threadIdx.x;
    const int n0 = blockIdx.x * 64;
    const int c  = t & 63;   // n within strip
    const int k0 = t >> 6;   // 0..3

    // coalesced f32 reads: for each k, 64 lanes read consecutive n
    for (int kk = 0; kk < DIM; kk += 4) {
        int k = kk + k0;
        tile[c][k] = __float2bfloat16(out_w[(size_t)k * VOCAB + n0 + c]);
    }
    __syncthreads();

    // emit fragment-major: thread = (tile_local = t>>6, lane = t&63)
    const int lane = t & 63;
    const int tl   = t >> 6;              // 0..3 local n-tile
    const int r16  = lane & 15;
    const int kq   = lane >> 4;
    const int gt   = (n0 >> 4) + tl;      // global n-tile
#pragma unroll
    for (int ks = 0; ks < 4; ++ks) {
        uint4 v = *reinterpret_cast<const uint4*>(&tile[tl * 16 + r16][ks * 32 + kq * 8]);
        *reinterpret_cast<uint4*>(Bf + ((size_t)(gt * 4 + ks) * 64 + lane) * 8) = v;
    }
}

// ---------------------------------------------------------------------------
// Persistent streaming GEMM: out[B,V] = gated @ Bt^T + bias, f32 out.
// 512 blocks x 512 thr (8 waves), ALL resident (2 blocks/CU). Block owns 16
// output rows (m0 = blockIdx.x*16); A-frags for those rows live in registers
// for the whole kernel (loaded once). Wave w sweeps n-tiles w, w+8, w+16, ...
// so per epoch the block's 8 waves write 8 ADJACENT 64-B row segments
// (512 B/row appended sequentially -> L2 merges into full lines, 8192
// quasi-sequential row streams device-wide) and read the SAME 32-KB B-window
// (shared across all 512 blocks via L2/L3; B is 8 MB, L3-resident).
// B loads are fully-coalesced 1-KB wave loads (fragment-major repack).
// Bias is folded in as the MFMA C-input. Swapped operands: D[n][m], lane's
// 4 acc regs = 4 consecutive n at fixed m -> one float4 store per tile.
// ---------------------------------------------------------------------------
__global__ __launch_bounds__(512, 4) void gemm_stream_kernel(
    const __hip_bfloat16* __restrict__ A,   // gated [B, D]
    const __hip_bfloat16* __restrict__ Bf,  // fragment-major weights
    const float* __restrict__ bias,         // [V]
    float* __restrict__ out)                // [B, V]
{
    const int lane = threadIdx.x & 63;
    const int wid  = threadIdx.x >> 6;      // 0..7 = tile interleave slot
    const int r16  = lane & 15;
    const int kq   = lane >> 4;             // 0..3
    const int m0   = blockIdx.x * 16;

    // A fragments for this block's 16 rows: resident in registers all kernel.
    short8 a[4];
#pragma unroll
    for (int ks = 0; ks < 4; ++ks)
        a[ks] = *reinterpret_cast<const short8*>(
            A + (size_t)(m0 + r16) * DIM + ks * 32 + kq * 8);

    const size_t outrow = (size_t)(m0 + r16) * VOCAB;

#pragma unroll 2
    for (int tt = 0; tt < NTILES / 8; ++tt) {
        const int tile = wid + (tt << 3);   // this wave's n-tile
        const int n0   = tile << 4;

        // C-in = bias (D row = n = kq*4 + reg)
        f32x4 acc = *reinterpret_cast<const f32x4*>(bias + n0 + kq * 4);

        short8 b[4];
#pragma unroll
        for (int ks = 0; ks < 4; ++ks)
            b[ks] = *reinterpret_cast<const short8*>(
                Bf + ((size_t)(tile * 4 + ks) * 64 + lane) * 8);

#pragma unroll
        for (int ks = 0; ks < 4; ++ks)
            acc = __builtin_amdgcn_mfma_f32_16x16x32_bf16(b[ks], a[ks], acc, 0, 0, 0);

        // store: 4 consecutive n at row m0+r16
        *reinterpret_cast<f32x4*>(out + outrow + n0 + kq * 4) = acc;
    }
}

// ---------------------------------------------------------------------------
extern "C" void kernel_launch(void* const* d_in, const int* in_sizes, int n_in,
                              void* d_out, int out_size, void* d_ws, size_t ws_size,
                              hipStream_t stream) {
    const float* x            = (const float*)d_in[0];
    const float* pattern_dict = (const float*)d_in[1];
    const float* attn_w       = (const float*)d_in[2];
    const float* attn_b       = (const float*)d_in[3];
    const float* self_w       = (const float*)d_in[4];
    const float* self_b       = (const float*)d_in[5];
    const float* out_w        = (const float*)d_in[6];
    const float* out_b        = (const float*)d_in[7];
    float* out = (float*)d_out;

    // workspace: gated bf16 [B,D] (2 MB) | Bf fragment-major bf16 (8.2 MB)
    __hip_bfloat16* gated = (__hip_bfloat16*)d_ws;
    __hip_bfloat16* Bf    = (__hip_bfloat16*)((char*)d_ws + (size_t)BATCH * DIM * 2);

    phaseA_kernel<<<BATCH / 4, 256, 0, stream>>>(
        x, attn_w, attn_b, pattern_dict, self_w, self_b, gated);
    repack_w_kernel<<<VOCAB / 64, 256, 0, stream>>>(out_w, Bf);
    gemm_stream_kernel<<<BATCH / 16, 512, 0, stream>>>(gated, Bf, out_b, out);
}

// Round 6
// 543.279 us; speedup vs baseline: 1.2743x; 1.2743x over previous
//
#include <hip/hip_runtime.h>
#include <hip/hip_bf16.h>

// Sizes (fixed by the reference)
#define BATCH 8192
#define DIM   128
#define NPAT  64
#define VOCAB 32000
#define NTILES (VOCAB / 16)   // 2000 n-tiles of 16 cols

// GEMM pass geometry: 512 persistent blocks x 8 waves; block owns 16 rows.
// Per pass: 8 waves x 5 tiles x 16 cols = 640 cols; 50 passes cover V=32000.
#define PASSW  640
#define WTILES 5
#define PASSES (VOCAB / PASSW)
#define LDSPAD 4              // row stride 644 f32: spreads banks evenly

typedef __attribute__((ext_vector_type(8))) short short8;   // 8 bf16 = 4 VGPRs
typedef __attribute__((ext_vector_type(4))) float f32x4;    // MFMA accum

// ---------------------------------------------------------------------------
// Phase A: per-row attention/softmax/rec/self-gate, all f32, output gated bf16.
// One wave per batch row, 4 rows (4 waves) per block.  (unchanged, ~15 us)
// ---------------------------------------------------------------------------
__global__ __launch_bounds__(256) void phaseA_kernel(
    const float* __restrict__ x,            // [B, D]
    const float* __restrict__ attn_w,       // [D, P]
    const float* __restrict__ attn_b,       // [P]
    const float* __restrict__ pattern_dict, // [P, D]
    const float* __restrict__ self_w,       // [D, D]
    const float* __restrict__ self_b,       // [D]
    __hip_bfloat16* __restrict__ gated)     // [B, D] bf16 out
{
    __shared__ float xs[4][DIM];
    __shared__ float wls[4][NPAT];
    __shared__ float recs[4][DIM];

    const int lane = threadIdx.x & 63;
    const int wid  = threadIdx.x >> 6;
    const int row  = blockIdx.x * 4 + wid;

    xs[wid][lane]      = x[row * DIM + lane];
    xs[wid][lane + 64] = x[row * DIM + 64 + lane];
    __syncthreads();

    float acc = attn_b[lane];
#pragma unroll 8
    for (int d = 0; d < DIM; ++d)
        acc += xs[wid][d] * attn_w[d * NPAT + lane];

    float m = acc;
#pragma unroll
    for (int o = 32; o; o >>= 1) m = fmaxf(m, __shfl_xor(m, o));
    float e = expf(acc - m);
    float s = e;
#pragma unroll
    for (int o = 32; o; o >>= 1) s += __shfl_xor(s, o);
    float w = e / s;
    wls[wid][lane] = w;
    __syncthreads();

    float r0 = 0.f, r1 = 0.f;
#pragma unroll 8
    for (int p = 0; p < NPAT; ++p) {
        float wp = wls[wid][p];
        r0 += wp * pattern_dict[p * DIM + lane];
        r1 += wp * pattern_dict[p * DIM + 64 + lane];
    }
    recs[wid][lane]      = r0;
    recs[wid][lane + 64] = r1;
    __syncthreads();

    float s0 = self_b[lane], s1 = self_b[lane + 64];
#pragma unroll 8
    for (int k = 0; k < DIM; ++k) {
        float rk = recs[wid][k];
        s0 += rk * self_w[k * DIM + lane];
        s1 += rk * self_w[k * DIM + 64 + lane];
    }

    float p0 = s0 - r0, p1 = s1 - r1;
    float ss = p0 * p0 + p1 * p1;
#pragma unroll
    for (int o = 32; o; o >>= 1) ss += __shfl_xor(ss, o);
    float mag = sqrtf(ss);
    float g = 1.f / (1.f + expf(-mag));

    gated[row * DIM + lane]      = __float2bfloat16(r0 * g);
    gated[row * DIM + 64 + lane] = __float2bfloat16(r1 * g);
}

// ---------------------------------------------------------------------------
// Repack: out_w [D=128, V] f32 -> Bf fragment-major bf16 (unchanged from R5,
// validated). Bf idx = ((tile*4 + ks)*64 + lane)*8 + j; lane = kq*16 + r16,
// holds Bt[n = tile*16 + r16][k = ks*32 + kq*8 + j]. GEMM B-loads are then
// single contiguous 1-KB wave loads.
// ---------------------------------------------------------------------------
__global__ __launch_bounds__(256) void repack_w_kernel(
    const float* __restrict__ out_w,        // [D, V]
    __hip_bfloat16* __restrict__ Bf)        // fragment-major [NTILES*4*64*8]
{
    __shared__ __hip_bfloat16 tile[64][136];

    const int t  = threadIdx.x;
    const int n0 = blockIdx.x * 64;
    const int c  = t & 63;
    const int k0 = t >> 6;

    for (int kk = 0; kk < DIM; kk += 4) {
        int k = kk + k0;
        tile[c][k] = __float2bfloat16(out_w[(size_t)k * VOCAB + n0 + c]);
    }
    __syncthreads();

    const int lane = t & 63;
    const int tl   = t >> 6;
    const int r16  = lane & 15;
    const int kq   = lane >> 4;
    const int gt   = (n0 >> 4) + tl;
#pragma unroll
    for (int ks = 0; ks < 4; ++ks) {
        uint4 v = *reinterpret_cast<const uint4*>(&tile[tl * 16 + r16][ks * 32 + kq * 8]);
        *reinterpret_cast<uint4*>(Bf + ((size_t)(gt * 4 + ks) * 64 + lane) * 8) = v;
    }
}

// ---------------------------------------------------------------------------
// Persistent GEMM with LDS-transposed streaming epilogue.
// 512 blocks x 512 thr (8 waves), 2 blocks/CU -> ALL resident. Block owns 16
// output rows; A-frags in registers for the whole kernel. Per pass (50 total):
//   compute: wave w computes tiles [p*40 + w*5 .. +4] (cols w*80..w*80+79),
//            4 KB of coalesced Bf loads + 20 MFMA, acc in VGPRs.
//   epilogue: acc -> LDS [16][644] (f32x4 writes, even bank spread), barrier,
//            each wave reads back 2 FULL rows (lane-consecutive f32x4, no
//            conflicts) adds bias and stores five 1-KB wave-instructions with
//            >=512 B contiguous segments -> fill-kernel-shaped DRAM writes.
// B L2 traffic: 512 blocks x 8 MB = 4.1 GB (vs 16.4 GB in R5). B window per
// pass = 160 KB, L2-resident; HBM refetch of B ~ one-time 8 MB.
// ---------------------------------------------------------------------------
__global__ __launch_bounds__(512, 4) void gemm_stream_kernel(
    const __hip_bfloat16* __restrict__ A,   // gated [B, D]
    const __hip_bfloat16* __restrict__ Bf,  // fragment-major weights
    const float* __restrict__ bias,         // [V]
    float* __restrict__ out)                // [B, V]
{
    __shared__ float lds[16][PASSW + LDSPAD];   // 41.2 KB

    const int lane = threadIdx.x & 63;
    const int wid  = threadIdx.x >> 6;      // 0..7
    const int r16  = lane & 15;
    const int kq   = lane >> 4;             // 0..3
    const int m0   = blockIdx.x * 16;

    // A fragments for this block's 16 rows: registers for the whole kernel.
    short8 a[4];
#pragma unroll
    for (int ks = 0; ks < 4; ++ks)
        a[ks] = *reinterpret_cast<const short8*>(
            A + (size_t)(m0 + r16) * DIM + ks * 32 + kq * 8);

    for (int p = 0; p < PASSES; ++p) {
        // ---- compute: 5 tiles, acc layout n=kq*4+reg (local), m=r16 ----
        f32x4 acc[WTILES];
        const int tile0 = p * (PASSW / 16) + wid * WTILES;
#pragma unroll
        for (int t = 0; t < WTILES; ++t) {
            const int tile = tile0 + t;
            short8 b[4];
#pragma unroll
            for (int ks = 0; ks < 4; ++ks)
                b[ks] = *reinterpret_cast<const short8*>(
                    Bf + ((size_t)(tile * 4 + ks) * 64 + lane) * 8);
            f32x4 c = {};
#pragma unroll
            for (int ks = 0; ks < 4; ++ks)
                c = __builtin_amdgcn_mfma_f32_16x16x32_bf16(b[ks], a[ks], c, 0, 0, 0);
            acc[t] = c;
        }

        // ---- transpose via LDS ----
        __syncthreads();   // protect previous pass's epilogue reads
#pragma unroll
        for (int t = 0; t < WTILES; ++t)
            *reinterpret_cast<f32x4*>(
                &lds[r16][wid * (WTILES * 16) + t * 16 + kq * 4]) = acc[t];
        __syncthreads();

        // ---- streaming epilogue: wave stores rows 2*wid, 2*wid+1 ----
        const int r0 = 2 * wid;
        const int colbase = p * PASSW;
#pragma unroll
        for (int s = 0; s < 5; ++s) {
            const int e   = s * 256 + lane * 4;     // flat f32 index in 2x640
            const int rr  = (e >= PASSW) ? 1 : 0;
            const int col = e - rr * PASSW;
            f32x4 v = *reinterpret_cast<const f32x4*>(&lds[r0 + rr][col]);
            v += *reinterpret_cast<const f32x4*>(bias + colbase + col);
            *reinterpret_cast<f32x4*>(
                out + (size_t)(m0 + r0 + rr) * VOCAB + colbase + col) = v;
        }
    }
}

// ---------------------------------------------------------------------------
extern "C" void kernel_launch(void* const* d_in, const int* in_sizes, int n_in,
                              void* d_out, int out_size, void* d_ws, size_t ws_size,
                              hipStream_t stream) {
    const float* x            = (const float*)d_in[0];
    const float* pattern_dict = (const float*)d_in[1];
    const float* attn_w       = (const float*)d_in[2];
    const float* attn_b       = (const float*)d_in[3];
    const float* self_w       = (const float*)d_in[4];
    const float* self_b       = (const float*)d_in[5];
    const float* out_w        = (const float*)d_in[6];
    const float* out_b        = (const float*)d_in[7];
    float* out = (float*)d_out;

    // workspace: gated bf16 [B,D] (2 MB) | Bf fragment-major bf16 (8.2 MB)
    __hip_bfloat16* gated = (__hip_bfloat16*)d_ws;
    __hip_bfloat16* Bf    = (__hip_bfloat16*)((char*)d_ws + (size_t)BATCH * DIM * 2);

    phaseA_kernel<<<BATCH / 4, 256, 0, stream>>>(
        x, attn_w, attn_b, pattern_dict, self_w, self_b, gated);
    repack_w_kernel<<<VOCAB / 64, 256, 0, stream>>>(out_w, Bf);
    gemm_stream_kernel<<<BATCH / 16, 512, 0, stream>>>(gated, Bf, out_b, out);
}

// Round 7
// 339.608 us; speedup vs baseline: 2.0385x; 1.5997x over previous
//
#include <hip/hip_runtime.h>
#include <hip/hip_bf16.h>

// Sizes (fixed by the reference)
#define BATCH 8192
#define DIM   128
#define NPAT  64
#define VOCAB 32000

// GEMM geometry: 512 blocks = 64 m-groups (x, fast) x 8 n-splits (y-ish).
// Block = 8 waves x 16 rows = 128 rows; n-split = 4000 cols = 25 passes x 160.
#define MGROUPS 64
#define NSPLIT  8
#define SPLITW  (VOCAB / NSPLIT)      // 4000
#define PASSW   160                   // cols per pass (10 n-tiles)
#define WT      (PASSW / 16)          // 10 tiles, shared by all waves
#define PASSES  (SPLITW / PASSW)      // 25
#define STAGEB  (PASSW * DIM * 2)     // 40960 B per pass window

typedef __attribute__((ext_vector_type(8))) short short8;   // 8 bf16 = 4 VGPRs
typedef __attribute__((ext_vector_type(4))) float f32x4;    // MFMA accum

// ---------------------------------------------------------------------------
// Phase A: per-row attention/softmax/rec/self-gate, all f32, output gated bf16.
// One wave per batch row, 4 rows (4 waves) per block.  (proven, ~15 us)
// ---------------------------------------------------------------------------
__global__ __launch_bounds__(256) void phaseA_kernel(
    const float* __restrict__ x,            // [B, D]
    const float* __restrict__ attn_w,       // [D, P]
    const float* __restrict__ attn_b,       // [P]
    const float* __restrict__ pattern_dict, // [P, D]
    const float* __restrict__ self_w,       // [D, D]
    const float* __restrict__ self_b,       // [D]
    __hip_bfloat16* __restrict__ gated)     // [B, D] bf16 out
{
    __shared__ float xs[4][DIM];
    __shared__ float wls[4][NPAT];
    __shared__ float recs[4][DIM];

    const int lane = threadIdx.x & 63;
    const int wid  = threadIdx.x >> 6;
    const int row  = blockIdx.x * 4 + wid;

    xs[wid][lane]      = x[row * DIM + lane];
    xs[wid][lane + 64] = x[row * DIM + 64 + lane];
    __syncthreads();

    float acc = attn_b[lane];
#pragma unroll 8
    for (int d = 0; d < DIM; ++d)
        acc += xs[wid][d] * attn_w[d * NPAT + lane];

    float m = acc;
#pragma unroll
    for (int o = 32; o; o >>= 1) m = fmaxf(m, __shfl_xor(m, o));
    float e = expf(acc - m);
    float s = e;
#pragma unroll
    for (int o = 32; o; o >>= 1) s += __shfl_xor(s, o);
    float w = e / s;
    wls[wid][lane] = w;
    __syncthreads();

    float r0 = 0.f, r1 = 0.f;
#pragma unroll 8
    for (int p = 0; p < NPAT; ++p) {
        float wp = wls[wid][p];
        r0 += wp * pattern_dict[p * DIM + lane];
        r1 += wp * pattern_dict[p * DIM + 64 + lane];
    }
    recs[wid][lane]      = r0;
    recs[wid][lane + 64] = r1;
    __syncthreads();

    float s0 = self_b[lane], s1 = self_b[lane + 64];
#pragma unroll 8
    for (int k = 0; k < DIM; ++k) {
        float rk = recs[wid][k];
        s0 += rk * self_w[k * DIM + lane];
        s1 += rk * self_w[k * DIM + 64 + lane];
    }

    float p0 = s0 - r0, p1 = s1 - r1;
    float ss = p0 * p0 + p1 * p1;
#pragma unroll
    for (int o = 32; o; o >>= 1) ss += __shfl_xor(ss, o);
    float mag = sqrtf(ss);
    float g = 1.f / (1.f + expf(-mag));

    gated[row * DIM + lane]      = __float2bfloat16(r0 * g);
    gated[row * DIM + 64 + lane] = __float2bfloat16(r1 * g);
}

// ---------------------------------------------------------------------------
// Repack: out_w [D=128, V] f32 -> Bf fragment-major bf16 (proven in R5/R6).
// Bf idx = ((tile*4 + ks)*64 + lane)*8 + j ; lane = kq*16 + r16 holds
// Bt[n = tile*16 + r16][k = ks*32 + kq*8 + j]. A pass's 10-tile window is a
// CONTIGUOUS 40960-B chunk -> stageable with linear global_load_lds.
// ---------------------------------------------------------------------------
__global__ __launch_bounds__(256) void repack_w_kernel(
    const float* __restrict__ out_w,        // [D, V]
    __hip_bfloat16* __restrict__ Bf)        // fragment-major [2000*4*64*8]
{
    __shared__ __hip_bfloat16 tile[64][136];

    const int t  = threadIdx.x;
    const int n0 = blockIdx.x * 64;
    const int c  = t & 63;
    const int k0 = t >> 6;

    for (int kk = 0; kk < DIM; kk += 4) {
        int k = kk + k0;
        tile[c][k] = __float2bfloat16(out_w[(size_t)k * VOCAB + n0 + c]);
    }
    __syncthreads();

    const int lane = t & 63;
    const int tl   = t >> 6;
    const int r16  = lane & 15;
    const int kq   = lane >> 4;
    const int gt   = (n0 >> 4) + tl;
#pragma unroll
    for (int ks = 0; ks < 4; ++ks) {
        uint4 v = *reinterpret_cast<const uint4*>(&tile[tl * 16 + r16][ks * 32 + kq * 8]);
        *reinterpret_cast<uint4*>(Bf + ((size_t)(gt * 4 + ks) * 64 + lane) * 8) = v;
    }
}

// ---------------------------------------------------------------------------
// GEMM: out = gated(bf16) @ Bt^T + bias, f32. B-reuse via LDS:
// block = 8 waves x 16 rows = 128 rows; per pass the 160-col B-window (40 KB,
// contiguous in Bf) is staged ONCE into LDS via global_load_lds dwordx4
// (double-buffered: stage pass p+1 while computing pass p; the single
// __syncthreads per pass drains vmcnt -> buffer ready). All 8 waves read the
// SAME B fragments from LDS (broadcast, conflict-free linear ds_read_b128).
// A-frags (16 VGPR) live in registers for the whole kernel.
// Swapped MFMA (D[n][m]): lane stores one f32x4 (4 consecutive n at its row);
// per pass each row receives a contiguous 640-B run.
// Grid: x = m-group (fast, 64) then n-split (slow, 8): same-n-split blocks
// are temporally adjacent -> B window L2-hot across blocks.
// Per-CU line traffic: reads 32k + writes 64k lines -> DRAM write floor binds.
// ---------------------------------------------------------------------------
__global__ __launch_bounds__(512, 4) void gemm_kernel(
    const __hip_bfloat16* __restrict__ A,   // gated [B, D]
    const __hip_bfloat16* __restrict__ Bf,  // fragment-major weights
    const float* __restrict__ bias,         // [V]
    float* __restrict__ out)                // [B, V]
{
    __shared__ __hip_bfloat16 bstage[2][PASSW * DIM];   // 2 x 40 KB

    const int lane = threadIdx.x & 63;
    const int w    = threadIdx.x >> 6;      // 0..7
    const int r16  = lane & 15;
    const int kq   = lane >> 4;             // 0..3
    const int mg   = blockIdx.x & (MGROUPS - 1);
    const int ns   = blockIdx.x >> 6;       // 0..7
    const int row  = mg * 128 + w * 16 + r16;
    const int ncol0 = ns * SPLITW;          // this block's first col
    const int tile0 = ns * (SPLITW / 16);   // this block's first n-tile

    // A fragments for this thread's row: registers for the whole kernel.
    short8 a[4];
#pragma unroll
    for (int ks = 0; ks < 4; ++ks)
        a[ks] = *reinterpret_cast<const short8*>(
            A + (size_t)row * DIM + ks * 32 + kq * 8);

    const size_t outrow = (size_t)row * VOCAB;

    // stage pass-p B-window (40960 B contiguous) into bstage[buf]
    // 512 threads... staging split by wave: wave w copies bytes
    // [w*5120, (w+1)*5120), 5 x 1024-B wave-instructions (16 B/lane).
    auto stage = [&](int p, int buf) {
        const char* src = (const char*)(Bf + (size_t)(tile0 + p * WT) * 4 * 64 * 8);
        char* dst = (char*)&bstage[buf][0];
#pragma unroll
        for (int i = 0; i < 5; ++i) {
            const int off = w * 5120 + i * 1024;
            __builtin_amdgcn_global_load_lds(
                (const void*)(src + off + lane * 16),
                (void*)(dst + off), 16, 0, 0);
        }
    };

    stage(0, 0);
    __syncthreads();

    int buf = 0;
    for (int p = 0; p < PASSES; ++p) {
        if (p + 1 < PASSES) stage(p + 1, buf ^ 1);   // issue early; drained at barrier

        const int colp = ncol0 + p * PASSW;
#pragma unroll
        for (int tt = 0; tt < WT; ++tt) {
            // B frags from LDS: linear per lane, broadcast across waves
            short8 b[4];
#pragma unroll
            for (int ks = 0; ks < 4; ++ks)
                b[ks] = *reinterpret_cast<const short8*>(
                    &bstage[buf][((tt * 4 + ks) * 64 + lane) * 8]);

            // C-in = bias (D row index = n = kq*4 + reg)
            f32x4 acc = *reinterpret_cast<const f32x4*>(bias + colp + tt * 16 + kq * 4);
#pragma unroll
            for (int ks = 0; ks < 4; ++ks)
                acc = __builtin_amdgcn_mfma_f32_16x16x32_bf16(b[ks], a[ks], acc, 0, 0, 0);

            // store: 4 consecutive n at this thread's row
            *reinterpret_cast<f32x4*>(out + outrow + colp + tt * 16 + kq * 4) = acc;
        }

        __syncthreads();   // drains stage vmcnt + orders LDS for next pass
        buf ^= 1;
    }
}

// ---------------------------------------------------------------------------
extern "C" void kernel_launch(void* const* d_in, const int* in_sizes, int n_in,
                              void* d_out, int out_size, void* d_ws, size_t ws_size,
                              hipStream_t stream) {
    const float* x            = (const float*)d_in[0];
    const float* pattern_dict = (const float*)d_in[1];
    const float* attn_w       = (const float*)d_in[2];
    const float* attn_b       = (const float*)d_in[3];
    const float* self_w       = (const float*)d_in[4];
    const float* self_b       = (const float*)d_in[5];
    const float* out_w        = (const float*)d_in[6];
    const float* out_b        = (const float*)d_in[7];
    float* out = (float*)d_out;

    // workspace: gated bf16 [B,D] (2 MB) | Bf fragment-major bf16 (8.2 MB)
    __hip_bfloat16* gated = (__hip_bfloat16*)d_ws;
    __hip_bfloat16* Bf    = (__hip_bfloat16*)((char*)d_ws + (size_t)BATCH * DIM * 2);

    phaseA_kernel<<<BATCH / 4, 256, 0, stream>>>(
        x, attn_w, attn_b, pattern_dict, self_w, self_b, gated);
    repack_w_kernel<<<VOCAB / 64, 256, 0, stream>>>(out_w, Bf);
    gemm_kernel<<<MGROUPS * NSPLIT, 512, 0, stream>>>(gated, Bf, out_b, out);
}